// Round 5
// baseline (78.998 us; speedup 1.0000x reference)
//
#include <hip/hip_runtime.h>
#include <math.h>

typedef unsigned long long u64;

#define S_DIM 1023
#define B_DIM 64
#define I_DIM 1024
#define CTX_DIM 784
#define CTX4 196          // CTX_DIM / 4
#define NWROWS 16         // 2^M buckets

#define LR_C 0.01f
#define WC_C 5.0f
#define LO_C (-6.906754778648554f)
#define HI_C ( 6.906754778648554f)

__device__ __forceinline__ float dot4(float4 a, float4 b) {
    return a.x * b.x + a.y * b.y + a.z * b.z + a.w * b.w;
}

__device__ __forceinline__ void nt_store4(float4* p, float4 v) {
    __builtin_nontemporal_store(v.x, &p->x);
    __builtin_nontemporal_store(v.y, &p->y);
    __builtin_nontemporal_store(v.z, &p->z);
    __builtin_nontemporal_store(v.w, &p->w);
}

__device__ __forceinline__ float4 upd4(float4 w, float4 a, float c) {
    float4 r;
    r.x = fminf(fmaxf(w.x - c * a.x, -WC_C), WC_C);
    r.y = fminf(fmaxf(w.y - c * a.y, -WC_C), WC_C);
    r.z = fminf(fmaxf(w.z - c * a.z, -WC_C), WC_C);
    r.w = fminf(fmaxf(w.w - c * a.w, -WC_C), WC_C);
    return r;
}

// ---------------- kernel A: context -> float4-transposed layout + bias row ----------------
__global__ __launch_bounds__(256) void prep_kernel(
    const float* __restrict__ context,   // [B, CTX]
    const float* __restrict__ bias,      // [1]
    float4* __restrict__ ctxT4,          // [CTX4][B]
    float* __restrict__ out_logits)      // [B, S+1]
{
    int g = blockIdx.x * 256 + threadIdx.x;      // 0 .. 196*64-1
    int k4 = g >> 6;
    int b  = g & 63;
    ctxT4[g] = *(const float4*)(context + (size_t)b * CTX_DIM + k4 * 4);
    if (g < B_DIM) out_logits[(size_t)g * (S_DIM + 1)] = bias[0];
}

// ---------------- kernel B: halfspace hash -> per-(s,k) membership masks ----------------
__global__ __launch_bounds__(256) void gln_idx_kernel(
    const float* __restrict__ cm,        // [S, 4, CTX]
    const float* __restrict__ cb,        // [S, 4]
    const float4* __restrict__ ctxT4,    // [CTX4][B]
    u64* __restrict__ mask_g)            // [S, 16] bucket membership bitmasks over b
{
    __shared__ float4 cm4[4 * CTX4];     // 12544 B
    __shared__ float  red[4][4][64];     // [q][m][b]
    __shared__ int    bits[4][64];
    __shared__ float  cb_lds[4];

    const int s = blockIdx.x;
    const int t = threadIdx.x;

    const float4* src = (const float4*)(cm + (size_t)s * 4 * CTX_DIM);
    for (int j = t; j < 4 * CTX4; j += 256) cm4[j] = src[j];
    if (t < 4) cb_lds[t] = cb[s * 4 + t];
    __syncthreads();

    const int b = t & 63;
    const int q = t >> 6;          // k-quarter
    float a0 = 0.f, a1 = 0.f, a2 = 0.f, a3 = 0.f;
    const int k0 = q * 49;
    #pragma unroll 7
    for (int kk = 0; kk < 49; ++kk) {
        int k4 = k0 + kk;
        float4 c4 = ctxT4[k4 * 64 + b];          // 16B/lane coalesced
        a0 += dot4(cm4[k4], c4);                 // wave-uniform -> LDS broadcast
        a1 += dot4(cm4[CTX4 + k4], c4);
        a2 += dot4(cm4[2 * CTX4 + k4], c4);
        a3 += dot4(cm4[3 * CTX4 + k4], c4);
    }
    red[q][0][b] = a0;
    red[q][1][b] = a1;
    red[q][2][b] = a2;
    red[q][3][b] = a3;
    __syncthreads();

    {
        int m = t >> 6, bb = t & 63;
        float sum = red[0][m][bb] + red[1][m][bb] + red[2][m][bb] + red[3][m][bb];
        bits[m][bb] = (sum > cb_lds[m]) ? 1 : 0;
    }
    __syncthreads();

    if (t < B_DIM) {   // wave 0 only: lane b
        int v = bits[0][t] + 2 * bits[1][t] + 4 * bits[2][t] + 8 * bits[3][t];
        u64 my = 0;
        #pragma unroll
        for (int kk = 0; kk < NWROWS; ++kk) {
            u64 mk = __ballot(v == kk);
            if (t == kk) my = mk;
        }
        if (t < NWROWS) mask_g[s * NWROWS + t] = my;
    }
}

// ---------------- kernel C: one wave per TWO (s,k) rows, pipelined member loop ----------------
__global__ __launch_bounds__(256) void gln_row2_kernel(
    const float* __restrict__ logit,     // [B, I]
    const float* __restrict__ target,    // [B]
    const float* __restrict__ weights,   // [S, 16, I]
    const u64*   __restrict__ mask_g,    // [S, 16]
    float* __restrict__ out_logits,      // [B, S+1]
    float* __restrict__ new_weights)     // [S, 16, I]
{
    const int wv = threadIdx.x >> 6;
    const int ln = threadIdx.x & 63;
    const int task0 = (blockIdx.x * 4 + wv) * 2;   // even; task0,task0+1 share s
    const int task1 = task0 + 1;
    const int s     = task0 >> 4;

    // both W rows -> registers (8 float4 in flight immediately)
    const float4* wr0 = (const float4*)weights + (size_t)task0 * 256;
    const float4* wr1 = (const float4*)weights + (size_t)task1 * 256;
    float4 w00 = wr0[ln], w01 = wr0[ln+64], w02 = wr0[ln+128], w03 = wr0[ln+192];
    float4 w10 = wr1[ln], w11 = wr1[ln+64], w12 = wr1[ln+128], w13 = wr1[ln+192];

    u64 m0 = mask_g[task0];
    u64 m1 = mask_g[task1];
    const int last0 = m0 ? (63 - __clzll(m0)) : -1;
    const int last1 = m1 ? (63 - __clzll(m1)) : -1;
    float c0 = 0.f, c1 = 0.f;

    // ---- software-pipelined member loop over the merged list (row0 then row1) ----
    int rA = -1, bA = -1;
    if (m0)      { bA = __builtin_ctzll(m0); m0 &= m0 - 1; rA = 0; }
    else if (m1) { bA = __builtin_ctzll(m1); m1 &= m1 - 1; rA = 1; }

    float4 aA0, aA1, aA2, aA3;
    if (bA >= 0) {
        const float4* lg = (const float4*)logit + (size_t)bA * 256;
        aA0 = lg[ln]; aA1 = lg[ln+64]; aA2 = lg[ln+128]; aA3 = lg[ln+192];
    }

    while (bA >= 0) {
        // prefetch next member's logit row BEFORE consuming current one
        int rB = -1, bB = -1;
        if (m0)      { bB = __builtin_ctzll(m0); m0 &= m0 - 1; rB = 0; }
        else if (m1) { bB = __builtin_ctzll(m1); m1 &= m1 - 1; rB = 1; }
        float4 aB0, aB1, aB2, aB3;
        if (bB >= 0) {
            const float4* lg = (const float4*)logit + (size_t)bB * 256;
            aB0 = lg[ln]; aB1 = lg[ln+64]; aB2 = lg[ln+128]; aB3 = lg[ln+192];
        }

        float acc;
        if (rA == 0)   // wave-uniform branch
            acc = dot4(aA0,w00) + dot4(aA1,w01) + dot4(aA2,w02) + dot4(aA3,w03);
        else
            acc = dot4(aA0,w10) + dot4(aA1,w11) + dot4(aA2,w12) + dot4(aA3,w13);
        #pragma unroll
        for (int off = 32; off; off >>= 1) acc += __shfl_xor(acc, off, 64);

        float o = fminf(fmaxf(acc, LO_C), HI_C);
        if (ln == 0) out_logits[(size_t)bA * (S_DIM + 1) + s + 1] = o;
        float sg = 1.0f / (1.0f + expf(-o));
        float cc = LR_C * (sg - target[bA]);
        if (rA == 0) { if (bA == last0) c0 = cc; }
        else         { if (bA == last1) c1 = cc; }

        bA = bB; rA = rB;
        if (bB >= 0) { aA0 = aB0; aA1 = aB1; aA2 = aB2; aA3 = aB3; }
    }

    // ---- update phase: stream both rows out (reload lastb's logit from L2) ----
    {
        float4* dst = (float4*)new_weights + (size_t)task0 * 256;
        if (last0 < 0) {
            nt_store4(dst + ln,       w00);
            nt_store4(dst + ln + 64,  w01);
            nt_store4(dst + ln + 128, w02);
            nt_store4(dst + ln + 192, w03);
        } else {
            const float4* lg = (const float4*)logit + (size_t)last0 * 256;
            float4 a0 = lg[ln], a1 = lg[ln+64], a2 = lg[ln+128], a3 = lg[ln+192];
            nt_store4(dst + ln,       upd4(w00, a0, c0));
            nt_store4(dst + ln + 64,  upd4(w01, a1, c0));
            nt_store4(dst + ln + 128, upd4(w02, a2, c0));
            nt_store4(dst + ln + 192, upd4(w03, a3, c0));
        }
    }
    {
        float4* dst = (float4*)new_weights + (size_t)task1 * 256;
        if (last1 < 0) {
            nt_store4(dst + ln,       w10);
            nt_store4(dst + ln + 64,  w11);
            nt_store4(dst + ln + 128, w12);
            nt_store4(dst + ln + 192, w13);
        } else {
            const float4* lg = (const float4*)logit + (size_t)last1 * 256;
            float4 a0 = lg[ln], a1 = lg[ln+64], a2 = lg[ln+128], a3 = lg[ln+192];
            nt_store4(dst + ln,       upd4(w10, a0, c1));
            nt_store4(dst + ln + 64,  upd4(w11, a1, c1));
            nt_store4(dst + ln + 128, upd4(w12, a2, c1));
            nt_store4(dst + ln + 192, upd4(w13, a3, c1));
        }
    }
}

extern "C" void kernel_launch(void* const* d_in, const int* in_sizes, int n_in,
                              void* d_out, int out_size, void* d_ws, size_t ws_size,
                              hipStream_t stream) {
    const float* logit   = (const float*)d_in[0];   // [B, I, 1]
    const float* context = (const float*)d_in[1];   // [B, CTX]
    const float* target  = (const float*)d_in[2];   // [B, 1]
    const float* cm      = (const float*)d_in[3];   // [1, S, 4, CTX]
    const float* cb      = (const float*)d_in[4];   // [1, S, 4, 1]
    const float* weights = (const float*)d_in[5];   // [1, S, 16, I]
    const float* bias    = (const float*)d_in[6];   // [1]

    float* out_logits  = (float*)d_out;                       // [B, S+1]
    float* new_weights = out_logits + (size_t)B_DIM * (S_DIM + 1);

    float4* ctxT4 = (float4*)d_ws;                            // [196][64] float4 (200704 B)
    u64*    mask_g = (u64*)((char*)d_ws + (size_t)CTX4 * B_DIM * sizeof(float4));

    prep_kernel<<<CTX4 * B_DIM / 256, 256, 0, stream>>>(context, bias, ctxT4, out_logits);
    gln_idx_kernel<<<S_DIM, 256, 0, stream>>>(cm, cb, ctxT4, mask_g);
    gln_row2_kernel<<<S_DIM * NWROWS / 8, 256, 0, stream>>>(logit, target, weights, mask_g,
                                                            out_logits, new_weights);
}